// Round 10
// baseline (63.986 us; speedup 1.0000x reference)
//
#include <hip/hip_runtime.h>

#define HOG_PI  3.14159265358979323846f
#define HOG_PI2 1.57079632679489661923f

__device__ __forceinline__ float dpp_from_left(float x) {  // lane i <- lane i-1
  return __int_as_float(__builtin_amdgcn_mov_dpp(__float_as_int(x), 0x130, 0xF, 0xF, true));
}
__device__ __forceinline__ float dpp_from_right(float x) {  // lane i <- lane i+1
  return __int_as_float(__builtin_amdgcn_mov_dpp(__float_as_int(x), 0x138, 0xF, 0xF, true));
}
__device__ __forceinline__ float med3(float a, float b, float c) {
  return __builtin_amdgcn_fmed3f(a, b, c);
}

// Accumulate 4 pixels (one float4 column) into 9-bin tent histogram h[9].
__device__ __forceinline__ void accum_quad(
    const float4 c0, const float4 c1, const float4 c2,
    const float4 p0, const float4 p1, const float4 p2,
    const float4 n0, const float4 n1, const float4 n2,
    int xq, float h[9]) {
  float dxv[3][4], dyv[3][4];
#pragma unroll
  for (int c = 0; c < 3; ++c) {
    const float4 cc = (c == 0) ? c0 : (c == 1) ? c1 : c2;
    const float4 pp = (c == 0) ? p0 : (c == 1) ? p1 : p2;
    const float4 nn = (c == 0) ? n0 : (c == 1) ? n1 : n2;
    float lf = dpp_from_left(cc.w);   // prev lane's cc.w (VALU, no DS pipe)
    float rf = dpp_from_right(cc.x);  // next lane's cc.x
    if (xq == 0) lf = cc.x;           // edge clamp overrides boundary lanes
    if (xq == 31) rf = cc.w;
    dxv[c][0] = cc.y - lf;
    dxv[c][1] = cc.z - cc.x;
    dxv[c][2] = cc.w - cc.y;
    dxv[c][3] = rf - cc.z;
    dyv[c][0] = nn.x - pp.x;
    dyv[c][1] = nn.y - pp.y;
    dyv[c][2] = nn.z - pp.z;
    dyv[c][3] = nn.w - pp.w;
  }
#pragma unroll
  for (int i = 0; i < 4; ++i) {
    // channel argmax, first-max wins on ties (strict >)
    float dxs = dxv[0][i], dys = dyv[0][i];
    float g = dxs * dxs + dys * dys;
    const float g1 = dxv[1][i] * dxv[1][i] + dyv[1][i] * dyv[1][i];
    if (g1 > g) { dxs = dxv[1][i]; dys = dyv[1][i]; g = g1; }
    const float g2 = dxv[2][i] * dxv[2][i] + dyv[2][i] * dyv[2][i];
    if (g2 > g) { dxs = dxv[2][i]; dys = dyv[2][i]; g = g2; }
    const float mag = __builtin_amdgcn_sqrtf(g);  // raw v_sqrt_f32
    // unsigned angle mod pi: flip so dy >= 0
    if (dys < 0.0f) { dys = -dys; dxs = -dxs; }
    const float ax = fabsf(dxs);
    const float mn = fminf(ax, dys), mx = fmaxf(ax, dys);
    const float a = mn * __builtin_amdgcn_rcpf(fmaxf(mx, 1e-30f));
    const float sq = a * a;
    float th = ((((0.0208351f * sq - 0.0851330f) * sq + 0.1801410f) * sq
                 - 0.3302995f) * sq + 0.9998660f) * a;
    if (dys > ax) th = HOG_PI2 - th;
    if (dxs < 0.0f) th = HOG_PI - th;
    const float pos = th * (9.0f / HOG_PI) - 0.5f;  // [-0.5, 8.5]
    // tent binning: bin k += mag*(1-|clamp(pos-k,-1,1)|)
#pragma unroll
    for (int k = 0; k < 9; ++k) {
      const float e = 1.0f - fabsf(med3(pos - (float)k, -1.0f, 1.0f));
      h[k] += mag * e;
    }
    // wrap terms: pos<0 -> bin8 gets -pos; pos>8 -> bin0 gets pos-8
    h[8] += mag * fmaxf(-pos, 0.0f);
    h[0] += mag * fmaxf(pos - 8.0f, 0.0f);
  }
}

// One block per image, 512 threads = 16 bands (m=t>>5) x 32 float4-cols (xq).
// NO __launch_bounds__: single-variable test of the VGPR-cap/spill hypothesis
// (R2/R3 showed caps catastrophically serialize; R7-R9 ran under a 128 cap).
__global__ void hog_kernel(
    const float* __restrict__ img, const int* __restrict__ targets,
    const int* __restrict__ camid, float* __restrict__ out, int B) {
  const int b = blockIdx.x;
  const int t = threadIdx.x;
  const float* im = img + (size_t)b * (3 * 256 * 128);

  __shared__ float cellh[16][8][9];  // each entry written exactly once

  const int xq = t & 31;   // float4 column 0..31
  const int m = t >> 5;    // cell band 0..15
  const int x0 = xq * 4;
  const int cx = xq >> 2;  // cell column 0..7
  const int r0 = m * 16;

  const float* ch0 = im;
  const float* ch1 = im + 32768;
  const float* ch2 = im + 65536;

  float h[9];
#pragma unroll
  for (int k = 0; k < 9; ++k) h[k] = 0.0f;

  const int rp = (r0 == 0) ? 0 : r0 - 1;
  float4 p0 = *(const float4*)(ch0 + rp * 128 + x0);
  float4 p1 = *(const float4*)(ch1 + rp * 128 + x0);
  float4 p2 = *(const float4*)(ch2 + rp * 128 + x0);
  float4 c0 = *(const float4*)(ch0 + r0 * 128 + x0);
  float4 c1 = *(const float4*)(ch1 + r0 * 128 + x0);
  float4 c2 = *(const float4*)(ch2 + r0 * 128 + x0);

  for (int r = 0; r < 16; ++r) {
    const int y = r0 + r;
    const int yn = (y == 255) ? 255 : y + 1;
    const float4 n0 = *(const float4*)(ch0 + yn * 128 + x0);
    const float4 n1 = *(const float4*)(ch1 + yn * 128 + x0);
    const float4 n2 = *(const float4*)(ch2 + yn * 128 + x0);
    accum_quad(c0, c1, c2, p0, p1, p2, n0, n1, n2, xq, h);
    p0 = c0; p1 = c1; p2 = c2;
    c0 = n0; c1 = n1; c2 = n2;
  }

  // flush: reduce across the 4 lanes sharing this cell column, write once
#pragma unroll
  for (int k = 0; k < 9; ++k) {
    float v = h[k];
    v += __shfl_xor(v, 1, 64);
    v += __shfl_xor(v, 2, 64);
    if ((xq & 3) == 0) cellh[m][cx][k] = v;
  }
  __syncthreads();

  float* outF = out + (size_t)b * 4096;
  if (t < 105) {
    const int by = t / 7;
    const int bx = t - by * 7;
    float v[36];
#pragma unroll
    for (int q = 0; q < 4; ++q) {
      const int cy = by + (q >> 1);
      const int ccx = bx + (q & 1);
#pragma unroll
      for (int k = 0; k < 9; ++k) v[q * 9 + k] = cellh[cy][ccx][k];
    }
    float ss = 0.0f;
#pragma unroll
    for (int jj = 0; jj < 36; ++jj) ss += v[jj] * v[jj];
    const float s1 = 1.0f / (sqrtf(ss) + 3.6f);  // sz*0.1 = 36*0.1
    float ss2 = 0.0f;
#pragma unroll
    for (int jj = 0; jj < 36; ++jj) {
      v[jj] = fminf(v[jj] * s1, 0.2f);
      ss2 += v[jj] * v[jj];
    }
    const float s2 = 1.0f / (sqrtf(ss2) + 1e-3f);
    float4* dst = (float4*)(outF + (by * 7 + bx) * 36);
#pragma unroll
    for (int q = 0; q < 9; ++q)
      dst[q] = make_float4(v[4 * q] * s2, v[4 * q + 1] * s2,
                           v[4 * q + 2] * s2, v[4 * q + 3] * s2);
  }
  // zero the pad region [3780, 4096)
  for (int i = 3780 + t; i < 4096; i += 512) outF[i] = 0.0f;
  // passthrough outputs
  if (t == 400) out[(size_t)B * 4096 + b] = (float)targets[b];
  if (t == 401) out[(size_t)B * 4096 + B + b] = (float)camid[b];
}

extern "C" void kernel_launch(void* const* d_in, const int* in_sizes, int n_in,
                              void* d_out, int out_size, void* d_ws, size_t ws_size,
                              hipStream_t stream) {
  const float* images = (const float*)d_in[0];
  const int* targets = (const int*)d_in[1];
  const int* camid = (const int*)d_in[2];
  float* out = (float*)d_out;
  const int B = in_sizes[1];  // 512
  hipLaunchKernelGGL(hog_kernel, dim3(B), dim3(512), 0, stream,
                     images, targets, camid, out, B);
}

// Round 11
// 63.783 us; speedup vs baseline: 1.0032x; 1.0032x over previous
//
#include <hip/hip_runtime.h>

#define HOG_PI  3.14159265358979323846f
#define HOG_PI2 1.57079632679489661923f

__device__ __forceinline__ float dpp_from_left(float x) {  // lane i <- lane i-1
  return __int_as_float(__builtin_amdgcn_mov_dpp(__float_as_int(x), 0x130, 0xF, 0xF, true));
}
__device__ __forceinline__ float dpp_from_right(float x) {  // lane i <- lane i+1
  return __int_as_float(__builtin_amdgcn_mov_dpp(__float_as_int(x), 0x138, 0xF, 0xF, true));
}
__device__ __forceinline__ float med3(float a, float b, float c) {
  return __builtin_amdgcn_fmed3f(a, b, c);
}

// Accumulate 4 pixels (one float4 column) into 9-bin tent histogram h[9].
__device__ __forceinline__ void accum_quad(
    const float4 c0, const float4 c1, const float4 c2,
    const float4 p0, const float4 p1, const float4 p2,
    const float4 n0, const float4 n1, const float4 n2,
    int xq, float h[9]) {
  float dxv[3][4], dyv[3][4];
#pragma unroll
  for (int c = 0; c < 3; ++c) {
    const float4 cc = (c == 0) ? c0 : (c == 1) ? c1 : c2;
    const float4 pp = (c == 0) ? p0 : (c == 1) ? p1 : p2;
    const float4 nn = (c == 0) ? n0 : (c == 1) ? n1 : n2;
    float lf = dpp_from_left(cc.w);   // prev lane's cc.w (VALU, no DS pipe)
    float rf = dpp_from_right(cc.x);  // next lane's cc.x
    if (xq == 0) lf = cc.x;           // edge clamp overrides boundary lanes
    if (xq == 31) rf = cc.w;
    dxv[c][0] = cc.y - lf;
    dxv[c][1] = cc.z - cc.x;
    dxv[c][2] = cc.w - cc.y;
    dxv[c][3] = rf - cc.z;
    dyv[c][0] = nn.x - pp.x;
    dyv[c][1] = nn.y - pp.y;
    dyv[c][2] = nn.z - pp.z;
    dyv[c][3] = nn.w - pp.w;
  }
#pragma unroll
  for (int i = 0; i < 4; ++i) {
    // channel argmax, first-max wins on ties (strict >)
    float dxs = dxv[0][i], dys = dyv[0][i];
    float g = dxs * dxs + dys * dys;
    const float g1 = dxv[1][i] * dxv[1][i] + dyv[1][i] * dyv[1][i];
    if (g1 > g) { dxs = dxv[1][i]; dys = dyv[1][i]; g = g1; }
    const float g2 = dxv[2][i] * dxv[2][i] + dyv[2][i] * dyv[2][i];
    if (g2 > g) { dxs = dxv[2][i]; dys = dyv[2][i]; g = g2; }
    const float mag = __builtin_amdgcn_sqrtf(g);  // raw v_sqrt_f32
    // unsigned angle mod pi: flip so dy >= 0
    if (dys < 0.0f) { dys = -dys; dxs = -dxs; }
    const float ax = fabsf(dxs);
    const float mn = fminf(ax, dys), mx = fmaxf(ax, dys);
    const float a = mn * __builtin_amdgcn_rcpf(fmaxf(mx, 1e-30f));
    const float sq = a * a;
    float th = ((((0.0208351f * sq - 0.0851330f) * sq + 0.1801410f) * sq
                 - 0.3302995f) * sq + 0.9998660f) * a;
    if (dys > ax) th = HOG_PI2 - th;
    if (dxs < 0.0f) th = HOG_PI - th;
    const float pos = th * (9.0f / HOG_PI) - 0.5f;  // [-0.5, 8.5]
    // tent binning: bin k += mag*(1-|clamp(pos-k,-1,1)|)
#pragma unroll
    for (int k = 0; k < 9; ++k) {
      const float e = 1.0f - fabsf(med3(pos - (float)k, -1.0f, 1.0f));
      h[k] += mag * e;
    }
    // wrap terms: pos<0 -> bin8 gets -pos; pos>8 -> bin0 gets pos-8
    h[8] += mag * fmaxf(-pos, 0.0f);
    h[0] += mag * fmaxf(pos - 8.0f, 0.0f);
  }
}

// One block per image, 512 threads = 16 bands (m=t>>5) x 32 float4-cols (xq).
// #pragma unroll 1 on the row loop: keep code ~2.7 KB, inside the 32 KB L1
// I-cache (full unroll = ~43 KB -> I$ thrash; the R5-R10 ~62us plateau's
// last-standing stall theory).
__global__ void hog_kernel(
    const float* __restrict__ img, const int* __restrict__ targets,
    const int* __restrict__ camid, float* __restrict__ out, int B) {
  const int b = blockIdx.x;
  const int t = threadIdx.x;
  const float* im = img + (size_t)b * (3 * 256 * 128);

  __shared__ float cellh[16][8][9];  // each entry written exactly once

  const int xq = t & 31;   // float4 column 0..31
  const int m = t >> 5;    // cell band 0..15
  const int x0 = xq * 4;
  const int cx = xq >> 2;  // cell column 0..7
  const int r0 = m * 16;

  const float* ch0 = im;
  const float* ch1 = im + 32768;
  const float* ch2 = im + 65536;

  float h[9];
#pragma unroll
  for (int k = 0; k < 9; ++k) h[k] = 0.0f;

  const int rp = (r0 == 0) ? 0 : r0 - 1;
  float4 p0 = *(const float4*)(ch0 + rp * 128 + x0);
  float4 p1 = *(const float4*)(ch1 + rp * 128 + x0);
  float4 p2 = *(const float4*)(ch2 + rp * 128 + x0);
  float4 c0 = *(const float4*)(ch0 + r0 * 128 + x0);
  float4 c1 = *(const float4*)(ch1 + r0 * 128 + x0);
  float4 c2 = *(const float4*)(ch2 + r0 * 128 + x0);

#pragma unroll 1
  for (int r = 0; r < 16; ++r) {
    const int y = r0 + r;
    const int yn = (y == 255) ? 255 : y + 1;
    const float4 n0 = *(const float4*)(ch0 + yn * 128 + x0);
    const float4 n1 = *(const float4*)(ch1 + yn * 128 + x0);
    const float4 n2 = *(const float4*)(ch2 + yn * 128 + x0);
    accum_quad(c0, c1, c2, p0, p1, p2, n0, n1, n2, xq, h);
    p0 = c0; p1 = c1; p2 = c2;
    c0 = n0; c1 = n1; c2 = n2;
  }

  // flush: reduce across the 4 lanes sharing this cell column, write once
#pragma unroll
  for (int k = 0; k < 9; ++k) {
    float v = h[k];
    v += __shfl_xor(v, 1, 64);
    v += __shfl_xor(v, 2, 64);
    if ((xq & 3) == 0) cellh[m][cx][k] = v;
  }
  __syncthreads();

  float* outF = out + (size_t)b * 4096;
  if (t < 105) {
    const int by = t / 7;
    const int bx = t - by * 7;
    float v[36];
#pragma unroll
    for (int q = 0; q < 4; ++q) {
      const int cy = by + (q >> 1);
      const int ccx = bx + (q & 1);
#pragma unroll
      for (int k = 0; k < 9; ++k) v[q * 9 + k] = cellh[cy][ccx][k];
    }
    float ss = 0.0f;
#pragma unroll
    for (int jj = 0; jj < 36; ++jj) ss += v[jj] * v[jj];
    const float s1 = 1.0f / (sqrtf(ss) + 3.6f);  // sz*0.1 = 36*0.1
    float ss2 = 0.0f;
#pragma unroll
    for (int jj = 0; jj < 36; ++jj) {
      v[jj] = fminf(v[jj] * s1, 0.2f);
      ss2 += v[jj] * v[jj];
    }
    const float s2 = 1.0f / (sqrtf(ss2) + 1e-3f);
    float4* dst = (float4*)(outF + (by * 7 + bx) * 36);
#pragma unroll
    for (int q = 0; q < 9; ++q)
      dst[q] = make_float4(v[4 * q] * s2, v[4 * q + 1] * s2,
                           v[4 * q + 2] * s2, v[4 * q + 3] * s2);
  }
  // zero the pad region [3780, 4096)
  for (int i = 3780 + t; i < 4096; i += 512) outF[i] = 0.0f;
  // passthrough outputs
  if (t == 400) out[(size_t)B * 4096 + b] = (float)targets[b];
  if (t == 401) out[(size_t)B * 4096 + B + b] = (float)camid[b];
}

extern "C" void kernel_launch(void* const* d_in, const int* in_sizes, int n_in,
                              void* d_out, int out_size, void* d_ws, size_t ws_size,
                              hipStream_t stream) {
  const float* images = (const float*)d_in[0];
  const int* targets = (const int*)d_in[1];
  const int* camid = (const int*)d_in[2];
  float* out = (float*)d_out;
  const int B = in_sizes[1];  // 512
  hipLaunchKernelGGL(hog_kernel, dim3(B), dim3(512), 0, stream,
                     images, targets, camid, out, B);
}

// Round 12
// 62.712 us; speedup vs baseline: 1.0203x; 1.0171x over previous
//
#include <hip/hip_runtime.h>

#define HOG_PI  3.14159265358979323846f
#define HOG_PI2 1.57079632679489661923f

__device__ __forceinline__ float dpp_from_left(float x) {  // lane i <- lane i-1
  return __int_as_float(__builtin_amdgcn_mov_dpp(__float_as_int(x), 0x130, 0xF, 0xF, true));
}
__device__ __forceinline__ float dpp_from_right(float x) {  // lane i <- lane i+1
  return __int_as_float(__builtin_amdgcn_mov_dpp(__float_as_int(x), 0x138, 0xF, 0xF, true));
}
__device__ __forceinline__ float med3(float a, float b, float c) {
  return __builtin_amdgcn_fmed3f(a, b, c);
}

// Accumulate 4 pixels (one float4 column) into 9-bin tent histogram h[9].
__device__ __forceinline__ void accum_quad(
    const float4 c0, const float4 c1, const float4 c2,
    const float4 p0, const float4 p1, const float4 p2,
    const float4 n0, const float4 n1, const float4 n2,
    int xq, float h[9]) {
  float dxv[3][4], dyv[3][4];
#pragma unroll
  for (int c = 0; c < 3; ++c) {
    const float4 cc = (c == 0) ? c0 : (c == 1) ? c1 : c2;
    const float4 pp = (c == 0) ? p0 : (c == 1) ? p1 : p2;
    const float4 nn = (c == 0) ? n0 : (c == 1) ? n1 : n2;
    float lf = dpp_from_left(cc.w);   // prev lane's cc.w (VALU, no DS pipe)
    float rf = dpp_from_right(cc.x);  // next lane's cc.x
    if (xq == 0) lf = cc.x;           // edge clamp overrides boundary lanes
    if (xq == 31) rf = cc.w;
    dxv[c][0] = cc.y - lf;
    dxv[c][1] = cc.z - cc.x;
    dxv[c][2] = cc.w - cc.y;
    dxv[c][3] = rf - cc.z;
    dyv[c][0] = nn.x - pp.x;
    dyv[c][1] = nn.y - pp.y;
    dyv[c][2] = nn.z - pp.z;
    dyv[c][3] = nn.w - pp.w;
  }
#pragma unroll
  for (int i = 0; i < 4; ++i) {
    // channel argmax, first-max wins on ties (strict >)
    float dxs = dxv[0][i], dys = dyv[0][i];
    float g = dxs * dxs + dys * dys;
    const float g1 = dxv[1][i] * dxv[1][i] + dyv[1][i] * dyv[1][i];
    if (g1 > g) { dxs = dxv[1][i]; dys = dyv[1][i]; g = g1; }
    const float g2 = dxv[2][i] * dxv[2][i] + dyv[2][i] * dyv[2][i];
    if (g2 > g) { dxs = dxv[2][i]; dys = dyv[2][i]; g = g2; }
    const float mag = __builtin_amdgcn_sqrtf(g);  // raw v_sqrt_f32
    // unsigned angle mod pi: flip so dy >= 0
    if (dys < 0.0f) { dys = -dys; dxs = -dxs; }
    const float ax = fabsf(dxs);
    const float mn = fminf(ax, dys), mx = fmaxf(ax, dys);
    const float a = mn * __builtin_amdgcn_rcpf(fmaxf(mx, 1e-30f));
    const float sq = a * a;
    float th = ((((0.0208351f * sq - 0.0851330f) * sq + 0.1801410f) * sq
                 - 0.3302995f) * sq + 0.9998660f) * a;
    if (dys > ax) th = HOG_PI2 - th;
    if (dxs < 0.0f) th = HOG_PI - th;
    const float pos = th * (9.0f / HOG_PI) - 0.5f;  // [-0.5, 8.5]
    // tent binning: bin k += mag*(1-|clamp(pos-k,-1,1)|)
#pragma unroll
    for (int k = 0; k < 9; ++k) {
      const float e = 1.0f - fabsf(med3(pos - (float)k, -1.0f, 1.0f));
      h[k] += mag * e;
    }
    // wrap terms: pos<0 -> bin8 gets -pos; pos>8 -> bin0 gets pos-8
    h[8] += mag * fmaxf(-pos, 0.0f);
    h[0] += mag * fmaxf(pos - 8.0f, 0.0f);
  }
}

// One block per image, 512 threads = 16 bands (m=t>>5) x 32 float4-cols (xq).
// SW pipeline: iteration r issues the loads for row r+1's 'n' BEFORE
// computing row r (loads stay in flight across the ~300-inst body ->
// L3 latency hidden). launch_bounds(512,2): VGPR<=128 keeps 2 blocks/CU.
__global__ __launch_bounds__(512, 2) void hog_kernel(
    const float* __restrict__ img, const int* __restrict__ targets,
    const int* __restrict__ camid, float* __restrict__ out, int B) {
  const int b = blockIdx.x;
  const int t = threadIdx.x;
  const float* im = img + (size_t)b * (3 * 256 * 128);

  __shared__ float cellh[16][8][9];  // each entry written exactly once

  const int xq = t & 31;   // float4 column 0..31
  const int m = t >> 5;    // cell band 0..15
  const int x0 = xq * 4;
  const int cx = xq >> 2;  // cell column 0..7
  const int r0 = m * 16;

  const float* ch0 = im;
  const float* ch1 = im + 32768;
  const float* ch2 = im + 65536;

  float h[9];
#pragma unroll
  for (int k = 0; k < 9; ++k) h[k] = 0.0f;

  const int rp = (r0 == 0) ? 0 : r0 - 1;
  float4 p0 = *(const float4*)(ch0 + rp * 128 + x0);
  float4 p1 = *(const float4*)(ch1 + rp * 128 + x0);
  float4 p2 = *(const float4*)(ch2 + rp * 128 + x0);
  float4 c0 = *(const float4*)(ch0 + r0 * 128 + x0);
  float4 c1 = *(const float4*)(ch1 + r0 * 128 + x0);
  float4 c2 = *(const float4*)(ch2 + r0 * 128 + x0);
  // n for row r=0 is row r0+1 (r0<=240 so no clamp needed)
  float4 n0 = *(const float4*)(ch0 + (r0 + 1) * 128 + x0);
  float4 n1 = *(const float4*)(ch1 + (r0 + 1) * 128 + x0);
  float4 n2 = *(const float4*)(ch2 + (r0 + 1) * 128 + x0);

#pragma unroll 1
  for (int r = 0; r < 16; ++r) {
    // prefetch row r+1's 'n' (row y+2, clamped); issued before any use of n*
    const int y2 = r0 + r + 2;
    const int yc = (y2 > 255) ? 255 : y2;
    const float4 f0 = *(const float4*)(ch0 + yc * 128 + x0);
    const float4 f1 = *(const float4*)(ch1 + yc * 128 + x0);
    const float4 f2 = *(const float4*)(ch2 + yc * 128 + x0);

    accum_quad(c0, c1, c2, p0, p1, p2, n0, n1, n2, xq, h);

    p0 = c0; p1 = c1; p2 = c2;
    c0 = n0; c1 = n1; c2 = n2;
    n0 = f0; n1 = f1; n2 = f2;
  }

  // flush: reduce across the 4 lanes sharing this cell column, write once
#pragma unroll
  for (int k = 0; k < 9; ++k) {
    float v = h[k];
    v += __shfl_xor(v, 1, 64);
    v += __shfl_xor(v, 2, 64);
    if ((xq & 3) == 0) cellh[m][cx][k] = v;
  }
  __syncthreads();

  float* outF = out + (size_t)b * 4096;
  if (t < 105) {
    const int by = t / 7;
    const int bx = t - by * 7;
    float v[36];
#pragma unroll
    for (int q = 0; q < 4; ++q) {
      const int cy = by + (q >> 1);
      const int ccx = bx + (q & 1);
#pragma unroll
      for (int k = 0; k < 9; ++k) v[q * 9 + k] = cellh[cy][ccx][k];
    }
    float ss = 0.0f;
#pragma unroll
    for (int jj = 0; jj < 36; ++jj) ss += v[jj] * v[jj];
    const float s1 = 1.0f / (sqrtf(ss) + 3.6f);  // sz*0.1 = 36*0.1
    float ss2 = 0.0f;
#pragma unroll
    for (int jj = 0; jj < 36; ++jj) {
      v[jj] = fminf(v[jj] * s1, 0.2f);
      ss2 += v[jj] * v[jj];
    }
    const float s2 = 1.0f / (sqrtf(ss2) + 1e-3f);
    float4* dst = (float4*)(outF + (by * 7 + bx) * 36);
#pragma unroll
    for (int q = 0; q < 9; ++q)
      dst[q] = make_float4(v[4 * q] * s2, v[4 * q + 1] * s2,
                           v[4 * q + 2] * s2, v[4 * q + 3] * s2);
  }
  // zero the pad region [3780, 4096)
  for (int i = 3780 + t; i < 4096; i += 512) outF[i] = 0.0f;
  // passthrough outputs
  if (t == 400) out[(size_t)B * 4096 + b] = (float)targets[b];
  if (t == 401) out[(size_t)B * 4096 + B + b] = (float)camid[b];
}

extern "C" void kernel_launch(void* const* d_in, const int* in_sizes, int n_in,
                              void* d_out, int out_size, void* d_ws, size_t ws_size,
                              hipStream_t stream) {
  const float* images = (const float*)d_in[0];
  const int* targets = (const int*)d_in[1];
  const int* camid = (const int*)d_in[2];
  float* out = (float*)d_out;
  const int B = in_sizes[1];  // 512
  hipLaunchKernelGGL(hog_kernel, dim3(B), dim3(512), 0, stream,
                     images, targets, camid, out, B);
}

// Round 13
// 46.439 us; speedup vs baseline: 1.3779x; 1.3504x over previous
//
#include <hip/hip_runtime.h>

#define HOG_PI  3.14159265358979323846f
#define HOG_PI2 1.57079632679489661923f

__device__ __forceinline__ float dpp_from_left(float x) {  // lane i <- lane i-1
  return __int_as_float(__builtin_amdgcn_mov_dpp(__float_as_int(x), 0x130, 0xF, 0xF, true));
}
__device__ __forceinline__ float dpp_from_right(float x) {  // lane i <- lane i+1
  return __int_as_float(__builtin_amdgcn_mov_dpp(__float_as_int(x), 0x138, 0xF, 0xF, true));
}

// Accumulate 4 pixels (one float4 column). Bin scatter goes to thread-private
// LDS rows (partT): 2 rows of 9 bins, even px -> row0, odd px -> row1
// (breaks the read->add->write dependency chain between adjacent pixels).
// Plain ds_read/ds_write — NO atomics (R1-R4: atomics serialize), NO 9-bin
// VALU scan (R7-R12: tent = 36 VALU ops/px was ~45% of the issue stream).
__device__ __forceinline__ void accum_quad(
    const float4 c0, const float4 c1, const float4 c2,
    const float4 p0, const float4 p1, const float4 p2,
    const float4 n0, const float4 n1, const float4 n2,
    int xq, float* __restrict__ partT) {
  float dxv[3][4], dyv[3][4];
#pragma unroll
  for (int c = 0; c < 3; ++c) {
    const float4 cc = (c == 0) ? c0 : (c == 1) ? c1 : c2;
    const float4 pp = (c == 0) ? p0 : (c == 1) ? p1 : p2;
    const float4 nn = (c == 0) ? n0 : (c == 1) ? n1 : n2;
    float lf = dpp_from_left(cc.w);   // prev lane's cc.w (VALU, no DS pipe)
    float rf = dpp_from_right(cc.x);  // next lane's cc.x
    if (xq == 0) lf = cc.x;           // edge clamp overrides boundary lanes
    if (xq == 31) rf = cc.w;
    dxv[c][0] = cc.y - lf;
    dxv[c][1] = cc.z - cc.x;
    dxv[c][2] = cc.w - cc.y;
    dxv[c][3] = rf - cc.z;
    dyv[c][0] = nn.x - pp.x;
    dyv[c][1] = nn.y - pp.y;
    dyv[c][2] = nn.z - pp.z;
    dyv[c][3] = nn.w - pp.w;
  }
#pragma unroll
  for (int i = 0; i < 4; ++i) {
    // channel argmax, first-max wins on ties (strict >)
    float dxs = dxv[0][i], dys = dyv[0][i];
    float g = dxs * dxs + dys * dys;
    const float g1 = dxv[1][i] * dxv[1][i] + dyv[1][i] * dyv[1][i];
    if (g1 > g) { dxs = dxv[1][i]; dys = dyv[1][i]; g = g1; }
    const float g2 = dxv[2][i] * dxv[2][i] + dyv[2][i] * dyv[2][i];
    if (g2 > g) { dxs = dxv[2][i]; dys = dyv[2][i]; g = g2; }
    const float mag = __builtin_amdgcn_sqrtf(g);  // raw v_sqrt_f32
    // unsigned angle mod pi: flip so dy >= 0
    if (dys < 0.0f) { dys = -dys; dxs = -dxs; }
    const float ax = fabsf(dxs);
    const float mn = fminf(ax, dys), mx = fmaxf(ax, dys);
    const float a = mn * __builtin_amdgcn_rcpf(fmaxf(mx, 1e-30f));
    const float sq = a * a;
    float th = ((((0.0208351f * sq - 0.0851330f) * sq + 0.1801410f) * sq
                 - 0.3302995f) * sq + 0.9998660f) * a;
    if (dys > ax) th = HOG_PI2 - th;
    if (dxs < 0.0f) th = HOG_PI - th;
    const float pos = th * (9.0f / HOG_PI) - 0.5f;  // [-0.5, 8.5]
    const float bf = floorf(pos);
    const float frac = pos - bf;
    const int b0 = (int)bf;  // [-1, 8]
    const int b0i = (b0 < 0) ? 8 : b0;
    const int b1i = (b0i == 8) ? 0 : b0i + 1;
    float* row = partT + (i & 1) * 9;   // even/odd px -> disjoint rows
    row[b0i] += mag * (1.0f - frac);    // ds_read + v_add + ds_write
    row[b1i] += mag * frac;             // b0i != b1i always
  }
}

// One block per image, 512 threads = 16 bands (m=t>>5) x 32 float4-cols (xq).
// Thread-private LDS scatter rows: stride 19 floats (odd -> 32-bank spread,
// 2 lanes/bank = conflict-free per wave access).
__global__ __launch_bounds__(512, 2) void hog_kernel(
    const float* __restrict__ img, const int* __restrict__ targets,
    const int* __restrict__ camid, float* __restrict__ out, int B) {
  const int b = blockIdx.x;
  const int t = threadIdx.x;
  const float* im = img + (size_t)b * (3 * 256 * 128);

  __shared__ float part[512 * 19];   // 38.9 KB: per-thread 2x9 bins + pad
  __shared__ float cellh[16][8][9];  // each entry written exactly once

  const int xq = t & 31;   // float4 column 0..31
  const int m = t >> 5;    // cell band 0..15
  const int x0 = xq * 4;
  const int cx = xq >> 2;  // cell column 0..7
  const int r0 = m * 16;

  float* partT = part + t * 19;
#pragma unroll
  for (int j = 0; j < 18; ++j) partT[j] = 0.0f;

  const float* ch0 = im;
  const float* ch1 = im + 32768;
  const float* ch2 = im + 65536;

  const int rp = (r0 == 0) ? 0 : r0 - 1;
  float4 p0 = *(const float4*)(ch0 + rp * 128 + x0);
  float4 p1 = *(const float4*)(ch1 + rp * 128 + x0);
  float4 p2 = *(const float4*)(ch2 + rp * 128 + x0);
  float4 c0 = *(const float4*)(ch0 + r0 * 128 + x0);
  float4 c1 = *(const float4*)(ch1 + r0 * 128 + x0);
  float4 c2 = *(const float4*)(ch2 + r0 * 128 + x0);
  // n for row r=0 is row r0+1 (r0<=240 so no clamp needed)
  float4 n0 = *(const float4*)(ch0 + (r0 + 1) * 128 + x0);
  float4 n1 = *(const float4*)(ch1 + (r0 + 1) * 128 + x0);
  float4 n2 = *(const float4*)(ch2 + (r0 + 1) * 128 + x0);

#pragma unroll 1
  for (int r = 0; r < 16; ++r) {
    // prefetch row r+1's 'n' (row y+2, clamped); issued before any use of n*
    const int y2 = r0 + r + 2;
    const int yc = (y2 > 255) ? 255 : y2;
    const float4 f0 = *(const float4*)(ch0 + yc * 128 + x0);
    const float4 f1 = *(const float4*)(ch1 + yc * 128 + x0);
    const float4 f2 = *(const float4*)(ch2 + yc * 128 + x0);

    accum_quad(c0, c1, c2, p0, p1, p2, n0, n1, n2, xq, partT);

    p0 = c0; p1 = c1; p2 = c2;
    c0 = n0; c1 = n1; c2 = n2;
    n0 = f0; n1 = f1; n2 = f2;
  }

  // flush: merge the 2 private rows, reduce across the 4 lanes sharing this
  // cell column, write once
#pragma unroll
  for (int k = 0; k < 9; ++k) {
    float v = partT[k] + partT[9 + k];
    v += __shfl_xor(v, 1, 64);
    v += __shfl_xor(v, 2, 64);
    if ((xq & 3) == 0) cellh[m][cx][k] = v;
  }
  __syncthreads();

  float* outF = out + (size_t)b * 4096;
  if (t < 105) {
    const int by = t / 7;
    const int bx = t - by * 7;
    float v[36];
#pragma unroll
    for (int q = 0; q < 4; ++q) {
      const int cy = by + (q >> 1);
      const int ccx = bx + (q & 1);
#pragma unroll
      for (int k = 0; k < 9; ++k) v[q * 9 + k] = cellh[cy][ccx][k];
    }
    float ss = 0.0f;
#pragma unroll
    for (int jj = 0; jj < 36; ++jj) ss += v[jj] * v[jj];
    const float s1 = 1.0f / (sqrtf(ss) + 3.6f);  // sz*0.1 = 36*0.1
    float ss2 = 0.0f;
#pragma unroll
    for (int jj = 0; jj < 36; ++jj) {
      v[jj] = fminf(v[jj] * s1, 0.2f);
      ss2 += v[jj] * v[jj];
    }
    const float s2 = 1.0f / (sqrtf(ss2) + 1e-3f);
    float4* dst = (float4*)(outF + (by * 7 + bx) * 36);
#pragma unroll
    for (int q = 0; q < 9; ++q)
      dst[q] = make_float4(v[4 * q] * s2, v[4 * q + 1] * s2,
                           v[4 * q + 2] * s2, v[4 * q + 3] * s2);
  }
  // zero the pad region [3780, 4096)
  for (int i = 3780 + t; i < 4096; i += 512) outF[i] = 0.0f;
  // passthrough outputs
  if (t == 400) out[(size_t)B * 4096 + b] = (float)targets[b];
  if (t == 401) out[(size_t)B * 4096 + B + b] = (float)camid[b];
}

extern "C" void kernel_launch(void* const* d_in, const int* in_sizes, int n_in,
                              void* d_out, int out_size, void* d_ws, size_t ws_size,
                              hipStream_t stream) {
  const float* images = (const float*)d_in[0];
  const int* targets = (const int*)d_in[1];
  const int* camid = (const int*)d_in[2];
  float* out = (float*)d_out;
  const int B = in_sizes[1];  // 512
  hipLaunchKernelGGL(hog_kernel, dim3(B), dim3(512), 0, stream,
                     images, targets, camid, out, B);
}

// Round 14
// 44.357 us; speedup vs baseline: 1.4425x; 1.0469x over previous
//
#include <hip/hip_runtime.h>

#define HOG_PI  3.14159265358979323846f
#define HOG_PI2 1.57079632679489661923f

__device__ __forceinline__ float dpp_from_left(float x) {  // lane i <- lane i-1
  return __int_as_float(__builtin_amdgcn_mov_dpp(__float_as_int(x), 0x130, 0xF, 0xF, true));
}
__device__ __forceinline__ float dpp_from_right(float x) {  // lane i <- lane i+1
  return __int_as_float(__builtin_amdgcn_mov_dpp(__float_as_int(x), 0x138, 0xF, 0xF, true));
}

// Accumulate 4 pixels (one float4 column). Bin scatter goes to thread-private
// LDS rows: ONE ROW PER PIXEL SLOT (4 rows x 9 bins) -> the 8 RMWs per quad
// form 4 independent chains of depth 2 (R13 had 2 rows = depth 4; LDS RMW
// round-trip was the suspected residual stall).
__device__ __forceinline__ void accum_quad(
    const float4 c0, const float4 c1, const float4 c2,
    const float4 p0, const float4 p1, const float4 p2,
    const float4 n0, const float4 n1, const float4 n2,
    int xq, float* __restrict__ partT) {
  float dxv[3][4], dyv[3][4];
#pragma unroll
  for (int c = 0; c < 3; ++c) {
    const float4 cc = (c == 0) ? c0 : (c == 1) ? c1 : c2;
    const float4 pp = (c == 0) ? p0 : (c == 1) ? p1 : p2;
    const float4 nn = (c == 0) ? n0 : (c == 1) ? n1 : n2;
    float lf = dpp_from_left(cc.w);   // prev lane's cc.w (VALU, no DS pipe)
    float rf = dpp_from_right(cc.x);  // next lane's cc.x
    if (xq == 0) lf = cc.x;           // edge clamp overrides boundary lanes
    if (xq == 31) rf = cc.w;
    dxv[c][0] = cc.y - lf;
    dxv[c][1] = cc.z - cc.x;
    dxv[c][2] = cc.w - cc.y;
    dxv[c][3] = rf - cc.z;
    dyv[c][0] = nn.x - pp.x;
    dyv[c][1] = nn.y - pp.y;
    dyv[c][2] = nn.z - pp.z;
    dyv[c][3] = nn.w - pp.w;
  }
#pragma unroll
  for (int i = 0; i < 4; ++i) {
    // channel argmax, first-max wins on ties (strict >)
    float dxs = dxv[0][i], dys = dyv[0][i];
    float g = dxs * dxs + dys * dys;
    const float g1 = dxv[1][i] * dxv[1][i] + dyv[1][i] * dyv[1][i];
    if (g1 > g) { dxs = dxv[1][i]; dys = dyv[1][i]; g = g1; }
    const float g2 = dxv[2][i] * dxv[2][i] + dyv[2][i] * dyv[2][i];
    if (g2 > g) { dxs = dxv[2][i]; dys = dyv[2][i]; g = g2; }
    const float mag = __builtin_amdgcn_sqrtf(g);  // raw v_sqrt_f32
    // unsigned angle mod pi: flip so dy >= 0
    if (dys < 0.0f) { dys = -dys; dxs = -dxs; }
    const float ax = fabsf(dxs);
    const float mn = fminf(ax, dys), mx = fmaxf(ax, dys);
    const float a = mn * __builtin_amdgcn_rcpf(fmaxf(mx, 1e-30f));
    const float sq = a * a;
    float th = ((((0.0208351f * sq - 0.0851330f) * sq + 0.1801410f) * sq
                 - 0.3302995f) * sq + 0.9998660f) * a;
    if (dys > ax) th = HOG_PI2 - th;
    if (dxs < 0.0f) th = HOG_PI - th;
    const float pos = th * (9.0f / HOG_PI) - 0.5f;  // [-0.5, 8.5]
    const float bf = floorf(pos);
    const float frac = pos - bf;
    const int b0 = (int)bf;  // [-1, 8]
    const int b0i = (b0 < 0) ? 8 : b0;
    const int b1i = (b0i == 8) ? 0 : b0i + 1;
    float* row = partT + i * 9;         // one private row per pixel slot
    row[b0i] += mag * (1.0f - frac);    // ds_read + v_add + ds_write
    row[b1i] += mag * frac;             // b0i != b1i always
  }
}

// One block per image, 512 threads = 16 bands (m=t>>5) x 32 float4-cols (xq).
// Scatter stride 37 floats (odd; banks hit = 5*lane mod 32 -> full spread,
// 2 lanes/bank = free). cellh OVERLAYS the scatter buffer (LDS budget):
// flush reads all partials to regs, barrier, then writes cellh in place.
__global__ __launch_bounds__(512, 2) void hog_kernel(
    const float* __restrict__ img, const int* __restrict__ targets,
    const int* __restrict__ camid, float* __restrict__ out, int B) {
  const int b = blockIdx.x;
  const int t = threadIdx.x;
  const float* im = img + (size_t)b * (3 * 256 * 128);

  __shared__ float lds[512 * 37];  // 74 KB; scatter rows, later cellh overlay
  float* const partT = lds + t * 37;

  const int xq = t & 31;   // float4 column 0..31
  const int m = t >> 5;    // cell band 0..15
  const int x0 = xq * 4;
  const int cx = xq >> 2;  // cell column 0..7
  const int r0 = m * 16;

#pragma unroll
  for (int j = 0; j < 36; ++j) partT[j] = 0.0f;

  const float* ch0 = im;
  const float* ch1 = im + 32768;
  const float* ch2 = im + 65536;

  const int rp = (r0 == 0) ? 0 : r0 - 1;
  float4 p0 = *(const float4*)(ch0 + rp * 128 + x0);
  float4 p1 = *(const float4*)(ch1 + rp * 128 + x0);
  float4 p2 = *(const float4*)(ch2 + rp * 128 + x0);
  float4 c0 = *(const float4*)(ch0 + r0 * 128 + x0);
  float4 c1 = *(const float4*)(ch1 + r0 * 128 + x0);
  float4 c2 = *(const float4*)(ch2 + r0 * 128 + x0);
  // n for row r=0 is row r0+1 (r0<=240 so no clamp needed)
  float4 n0 = *(const float4*)(ch0 + (r0 + 1) * 128 + x0);
  float4 n1 = *(const float4*)(ch1 + (r0 + 1) * 128 + x0);
  float4 n2 = *(const float4*)(ch2 + (r0 + 1) * 128 + x0);

#pragma unroll 1
  for (int r = 0; r < 16; ++r) {
    // prefetch row r+1's 'n' (row y+2, clamped); issued before any use of n*
    const int y2 = r0 + r + 2;
    const int yc = (y2 > 255) ? 255 : y2;
    const float4 f0 = *(const float4*)(ch0 + yc * 128 + x0);
    const float4 f1 = *(const float4*)(ch1 + yc * 128 + x0);
    const float4 f2 = *(const float4*)(ch2 + yc * 128 + x0);

    accum_quad(c0, c1, c2, p0, p1, p2, n0, n1, n2, xq, partT);

    p0 = c0; p1 = c1; p2 = c2;
    c0 = n0; c1 = n1; c2 = n2;
    n0 = f0; n1 = f1; n2 = f2;
  }

  // flush: pull the 4 private rows into registers (all reads BEFORE the
  // barrier so the cellh overlay can't clobber unread data)
  float hv[9];
#pragma unroll
  for (int k = 0; k < 9; ++k)
    hv[k] = (partT[k] + partT[9 + k]) + (partT[18 + k] + partT[27 + k]);
  __syncthreads();

  float (*cellh)[8][9] = (float (*)[8][9])lds;  // overlay
#pragma unroll
  for (int k = 0; k < 9; ++k) {
    float v = hv[k];
    v += __shfl_xor(v, 1, 64);
    v += __shfl_xor(v, 2, 64);
    if ((xq & 3) == 0) cellh[m][cx][k] = v;
  }
  __syncthreads();

  float* outF = out + (size_t)b * 4096;
  if (t < 105) {
    const int by = t / 7;
    const int bx = t - by * 7;
    float v[36];
#pragma unroll
    for (int q = 0; q < 4; ++q) {
      const int cy = by + (q >> 1);
      const int ccx = bx + (q & 1);
#pragma unroll
      for (int k = 0; k < 9; ++k) v[q * 9 + k] = cellh[cy][ccx][k];
    }
    float ss = 0.0f;
#pragma unroll
    for (int jj = 0; jj < 36; ++jj) ss += v[jj] * v[jj];
    const float s1 = 1.0f / (sqrtf(ss) + 3.6f);  // sz*0.1 = 36*0.1
    float ss2 = 0.0f;
#pragma unroll
    for (int jj = 0; jj < 36; ++jj) {
      v[jj] = fminf(v[jj] * s1, 0.2f);
      ss2 += v[jj] * v[jj];
    }
    const float s2 = 1.0f / (sqrtf(ss2) + 1e-3f);
    float4* dst = (float4*)(outF + (by * 7 + bx) * 36);
#pragma unroll
    for (int q = 0; q < 9; ++q)
      dst[q] = make_float4(v[4 * q] * s2, v[4 * q + 1] * s2,
                           v[4 * q + 2] * s2, v[4 * q + 3] * s2);
  }
  // zero the pad region [3780, 4096)
  for (int i = 3780 + t; i < 4096; i += 512) outF[i] = 0.0f;
  // passthrough outputs
  if (t == 400) out[(size_t)B * 4096 + b] = (float)targets[b];
  if (t == 401) out[(size_t)B * 4096 + B + b] = (float)camid[b];
}

extern "C" void kernel_launch(void* const* d_in, const int* in_sizes, int n_in,
                              void* d_out, int out_size, void* d_ws, size_t ws_size,
                              hipStream_t stream) {
  const float* images = (const float*)d_in[0];
  const int* targets = (const int*)d_in[1];
  const int* camid = (const int*)d_in[2];
  float* out = (float*)d_out;
  const int B = in_sizes[1];  // 512
  hipLaunchKernelGGL(hog_kernel, dim3(B), dim3(512), 0, stream,
                     images, targets, camid, out, B);
}